// Round 1
// baseline (5162.859 us; speedup 1.0000x reference)
//
#include <hip/hip_runtime.h>

#define N_TOTAL 150000
#define DIM 128
#define NNZ_E 1500000

__device__ __forceinline__ void atomic_add_f32(float* p, float v) {
    // relaxed device-scope fp32 atomic -> global_atomic_add_f32 (no CAS loop)
    __hip_atomic_fetch_add(p, v, __ATOMIC_RELAXED, __HIP_MEMORY_SCOPE_AGENT);
}

// dst[sidx[e]] += vals[e] * src[gidx[e]]   (32 lanes per edge, float4 per lane)
__global__ void scatter_kernel(const float* __restrict__ src,
                               const float* __restrict__ vals,
                               const int* __restrict__ gidx,
                               const int* __restrict__ sidx,
                               float* __restrict__ dst, int nnz) {
    int gid = blockIdx.x * blockDim.x + threadIdx.x;
    int e = gid >> 5;   // 32 lanes per edge
    int lane = gid & 31;
    if (e >= nnz) return;
    int g = gidx[e];
    int s = sidx[e];
    float v = vals[e];
    const float4* s4 = (const float4*)(src + (size_t)g * DIM);
    float4 x = s4[lane];
    float* d = dst + (size_t)s * DIM + lane * 4;
    atomic_add_f32(d + 0, v * x.x);
    atomic_add_f32(d + 1, v * x.y);
    atomic_add_f32(d + 2, v * x.z);
    atomic_add_f32(d + 3, v * x.w);
}

// one 64-lane wave per row: out = (h2 - mu) * rsqrt(var+eps) * gamma + beta + ego
__global__ void ln_residual_kernel(const float* __restrict__ h2,
                                   const float* __restrict__ ego,
                                   const float* __restrict__ gamma,
                                   const float* __restrict__ beta,
                                   float* __restrict__ out, int n) {
    int gid = blockIdx.x * blockDim.x + threadIdx.x;
    int row = gid >> 6;
    int lane = gid & 63;
    if (row >= n) return;
    const float2* x2 = (const float2*)(h2 + (size_t)row * DIM);
    float2 x = x2[lane];
    float s = x.x + x.y;
    float sq = x.x * x.x + x.y * x.y;
    #pragma unroll
    for (int off = 32; off > 0; off >>= 1) {
        s  += __shfl_xor(s, off, 64);
        sq += __shfl_xor(sq, off, 64);
    }
    float mu = s * (1.0f / DIM);
    float var = sq * (1.0f / DIM) - mu * mu;
    float rs = rsqrtf(var + 1e-5f);
    const float2* e2 = (const float2*)(ego + (size_t)row * DIM);
    float2 eg = e2[lane];
    float2 g  = ((const float2*)gamma)[lane];
    float2 b  = ((const float2*)beta)[lane];
    float2 o;
    o.x = (x.x - mu) * rs * g.x + b.x + eg.x;
    o.y = (x.y - mu) * rs * g.y + b.y + eg.y;
    ((float2*)(out + (size_t)row * DIM))[lane] = o;
}

extern "C" void kernel_launch(void* const* d_in, const int* in_sizes, int n_in,
                              void* d_out, int out_size, void* d_ws, size_t ws_size,
                              hipStream_t stream) {
    const float* ego   = (const float*)d_in[0];
    const float* vals  = (const float*)d_in[1];
    const float* gamma = (const float*)d_in[2];
    const float* beta  = (const float*)d_in[3];
    const int*   rows  = (const int*)d_in[4];
    const int*   cols  = (const int*)d_in[5];
    float* out = (float*)d_out;              // doubles as h2 accumulator
    float* h   = (float*)d_ws;               // hop-1 accumulator, N*D floats

    size_t hbytes = (size_t)N_TOTAL * DIM * sizeof(float);
    hipMemsetAsync(h, 0, hbytes, stream);
    hipMemsetAsync(out, 0, hbytes, stream);

    const int block = 256;
    long total = (long)NNZ_E * 32;           // 32 lanes per edge
    int grid = (int)((total + block - 1) / block);

    // pass 1: h[cols[e]] += vals[e] * ego[rows[e]]
    scatter_kernel<<<grid, block, 0, stream>>>(ego, vals, rows, cols, h, NNZ_E);
    // pass 2: h2[rows[e]] += vals[e] * h[cols[e]]
    scatter_kernel<<<grid, block, 0, stream>>>(h, vals, cols, rows, out, NNZ_E);

    int lngrid = (N_TOTAL * 64 + block - 1) / block;
    ln_residual_kernel<<<lngrid, block, 0, stream>>>(out, ego, gamma, beta, out, N_TOTAL);
}

// Round 2
// 664.601 us; speedup vs baseline: 7.7684x; 7.7684x over previous
//
#include <hip/hip_runtime.h>

#define N_TOTAL 150000
#define DIM 128
#define NNZ_E 1500000
#define N2 (2 * N_TOTAL)
#define SCAN_CHUNK 2048
#define NB ((N2 + SCAN_CHUNK - 1) / SCAN_CHUNK)   // 147 blocks

// ---------------- CSR build ----------------

__global__ void hist_kernel(const int* __restrict__ rows, const int* __restrict__ cols,
                            int* __restrict__ cnt) {
    int e = blockIdx.x * blockDim.x + threadIdx.x;
    int stride = gridDim.x * blockDim.x;
    for (; e < NNZ_E; e += stride) {
        atomicAdd(&cnt[cols[e]], 1);              // pass-1 dest = col
        atomicAdd(&cnt[N_TOTAL + rows[e]], 1);    // pass-2 dest = row
    }
}

__global__ void scanA(const int* __restrict__ cnt, int* __restrict__ bsums) {
    __shared__ int lds[256];
    int t = threadIdx.x;
    int base = blockIdx.x * SCAN_CHUNK + t * 8;
    int s = 0;
    #pragma unroll
    for (int j = 0; j < 8; j++) { int i = base + j; if (i < N2) s += cnt[i]; }
    lds[t] = s; __syncthreads();
    for (int off = 128; off > 0; off >>= 1) {
        if (t < off) lds[t] += lds[t + off];
        __syncthreads();
    }
    if (t == 0) bsums[blockIdx.x] = lds[0];
}

__global__ void scanB(int* __restrict__ bsums) {
    __shared__ int lds[256];
    int t = threadIdx.x;
    int v = (t < NB) ? bsums[t] : 0;
    lds[t] = v; __syncthreads();
    for (int off = 1; off < 256; off <<= 1) {
        int a = (t >= off) ? lds[t - off] : 0;
        __syncthreads();
        lds[t] += a;
        __syncthreads();
    }
    if (t < NB) bsums[t] = lds[t] - v;   // exclusive
}

__global__ void scanC(const int* __restrict__ cnt, const int* __restrict__ bsums,
                      int* __restrict__ offs) {
    __shared__ int lds[256];
    int t = threadIdx.x;
    int base = blockIdx.x * SCAN_CHUNK + t * 8;
    int v[8]; int s = 0;
    #pragma unroll
    for (int j = 0; j < 8; j++) { int i = base + j; v[j] = (i < N2) ? cnt[i] : 0; s += v[j]; }
    lds[t] = s; __syncthreads();
    for (int off = 1; off < 256; off <<= 1) {
        int a = (t >= off) ? lds[t - off] : 0;
        __syncthreads();
        lds[t] += a;
        __syncthreads();
    }
    int run = bsums[blockIdx.x] + lds[t] - s;   // exclusive block-local + global base
    #pragma unroll
    for (int j = 0; j < 8; j++) { int i = base + j; if (i < N2) offs[i] = run; run += v[j]; }
    if (blockIdx.x == 0 && t == 0) offs[N2] = 2 * NNZ_E;   // tail sentinel
}

__global__ void scatter_build(const int* __restrict__ rows, const int* __restrict__ cols,
                              const float* __restrict__ vals, const int* __restrict__ offs,
                              int* __restrict__ curs, int* __restrict__ sSrc,
                              float* __restrict__ sVal) {
    int e = blockIdx.x * blockDim.x + threadIdx.x;
    int stride = gridDim.x * blockDim.x;
    for (; e < NNZ_E; e += stride) {
        int r = rows[e], c = cols[e];
        float v = vals[e];
        int pA = offs[c] + atomicAdd(&curs[c], 1);             // sorted-by-col region
        sSrc[pA] = r; sVal[pA] = v;
        int pB = offs[N_TOTAL + r] + atomicAdd(&curs[N_TOTAL + r], 1);  // sorted-by-row region
        sSrc[pB] = c; sVal[pB] = v;
    }
}

// ---------------- gather passes ----------------

// h[row] = sum_e val_e * src[src_e]   (32 lanes per row, float4/lane)
__global__ void gather1(const float* __restrict__ src, const int* __restrict__ offs,
                        const int* __restrict__ sSrc, const float* __restrict__ sVal,
                        float* __restrict__ dst) {
    int gid = blockIdx.x * blockDim.x + threadIdx.x;
    int row = gid >> 5, lane = gid & 31;
    if (row >= N_TOTAL) return;
    int beg = offs[row], end = offs[row + 1];
    float4 acc = make_float4(0.f, 0.f, 0.f, 0.f);
    const float4* s4 = (const float4*)src;
    for (int i = beg; i < end; i++) {
        int s = sSrc[i]; float v = sVal[i];
        float4 x = s4[(size_t)s * 32 + lane];
        acc.x += v * x.x; acc.y += v * x.y; acc.z += v * x.z; acc.w += v * x.w;
    }
    ((float4*)dst)[(size_t)row * 32 + lane] = acc;
}

// h2[row] = sum_e val_e * h[src_e], then LN + gamma/beta + ego residual, write out
__global__ void gather2_ln(const float* __restrict__ h, const int* __restrict__ offs,
                           const int* __restrict__ sSrc, const float* __restrict__ sVal,
                           const float* __restrict__ ego, const float* __restrict__ gamma,
                           const float* __restrict__ beta, float* __restrict__ out) {
    int gid = blockIdx.x * blockDim.x + threadIdx.x;
    int row = gid >> 5, lane = gid & 31;
    if (row >= N_TOTAL) return;
    int beg = offs[N_TOTAL + row], end = offs[N_TOTAL + row + 1];
    float4 acc = make_float4(0.f, 0.f, 0.f, 0.f);
    const float4* s4 = (const float4*)h;
    for (int i = beg; i < end; i++) {
        int s = sSrc[i]; float v = sVal[i];
        float4 x = s4[(size_t)s * 32 + lane];
        acc.x += v * x.x; acc.y += v * x.y; acc.z += v * x.z; acc.w += v * x.w;
    }
    // cross-lane mean/var over the 32-lane row group (xor masks <32 stay in-group)
    float s = acc.x + acc.y + acc.z + acc.w;
    float sq = acc.x * acc.x + acc.y * acc.y + acc.z * acc.z + acc.w * acc.w;
    #pragma unroll
    for (int off = 16; off > 0; off >>= 1) {
        s  += __shfl_xor(s, off, 64);
        sq += __shfl_xor(sq, off, 64);
    }
    float mu = s * (1.0f / DIM);
    float var = sq * (1.0f / DIM) - mu * mu;
    float rs = rsqrtf(var + 1e-5f);
    float4 g = ((const float4*)gamma)[lane];
    float4 b = ((const float4*)beta)[lane];
    float4 e4 = ((const float4*)ego)[(size_t)row * 32 + lane];
    float4 o;
    o.x = (acc.x - mu) * rs * g.x + b.x + e4.x;
    o.y = (acc.y - mu) * rs * g.y + b.y + e4.y;
    o.z = (acc.z - mu) * rs * g.z + b.z + e4.z;
    o.w = (acc.w - mu) * rs * g.w + b.w + e4.w;
    ((float4*)out)[(size_t)row * 32 + lane] = o;
}

// ---------------- fallback (atomic) path, used only if ws too small ----------------

__device__ __forceinline__ void atomic_add_f32(float* p, float v) {
    __hip_atomic_fetch_add(p, v, __ATOMIC_RELAXED, __HIP_MEMORY_SCOPE_AGENT);
}

__global__ void scatter_kernel(const float* __restrict__ src, const float* __restrict__ vals,
                               const int* __restrict__ gidx, const int* __restrict__ sidx,
                               float* __restrict__ dst, int nnz) {
    int gid = blockIdx.x * blockDim.x + threadIdx.x;
    int e = gid >> 5, lane = gid & 31;
    if (e >= nnz) return;
    int g = gidx[e], sdx = sidx[e];
    float v = vals[e];
    float4 x = ((const float4*)(src + (size_t)g * DIM))[lane];
    float* d = dst + (size_t)sdx * DIM + lane * 4;
    atomic_add_f32(d + 0, v * x.x);
    atomic_add_f32(d + 1, v * x.y);
    atomic_add_f32(d + 2, v * x.z);
    atomic_add_f32(d + 3, v * x.w);
}

__global__ void ln_residual_kernel(const float* __restrict__ h2, const float* __restrict__ ego,
                                   const float* __restrict__ gamma, const float* __restrict__ beta,
                                   float* __restrict__ out, int n) {
    int gid = blockIdx.x * blockDim.x + threadIdx.x;
    int row = gid >> 6, lane = gid & 63;
    if (row >= n) return;
    float2 x = ((const float2*)(h2 + (size_t)row * DIM))[lane];
    float s = x.x + x.y, sq = x.x * x.x + x.y * x.y;
    #pragma unroll
    for (int off = 32; off > 0; off >>= 1) { s += __shfl_xor(s, off, 64); sq += __shfl_xor(sq, off, 64); }
    float mu = s * (1.0f / DIM);
    float var = sq * (1.0f / DIM) - mu * mu;
    float rs = rsqrtf(var + 1e-5f);
    float2 eg = ((const float2*)(ego + (size_t)row * DIM))[lane];
    float2 g = ((const float2*)gamma)[lane];
    float2 b = ((const float2*)beta)[lane];
    float2 o;
    o.x = (x.x - mu) * rs * g.x + b.x + eg.x;
    o.y = (x.y - mu) * rs * g.y + b.y + eg.y;
    ((float2*)(out + (size_t)row * DIM))[lane] = o;
}

// ---------------- launch ----------------

extern "C" void kernel_launch(void* const* d_in, const int* in_sizes, int n_in,
                              void* d_out, int out_size, void* d_ws, size_t ws_size,
                              hipStream_t stream) {
    const float* ego   = (const float*)d_in[0];
    const float* vals  = (const float*)d_in[1];
    const float* gamma = (const float*)d_in[2];
    const float* beta  = (const float*)d_in[3];
    const int*   rows  = (const int*)d_in[4];
    const int*   cols  = (const int*)d_in[5];
    float* out = (float*)d_out;

    // workspace layout
    const size_t H_B     = (size_t)N_TOTAL * DIM * sizeof(float);   // 76.8 MB
    const size_t SSRC_B  = (size_t)2 * NNZ_E * sizeof(int);         // 12 MB
    const size_t SVAL_B  = (size_t)2 * NNZ_E * sizeof(float);       // 12 MB
    const size_t CNT_B   = (size_t)N2 * sizeof(int);                // 1.2 MB
    const size_t OFFS_B  = ((size_t)N2 + 4) * sizeof(int);          // 1.2 MB (padded)
    const size_t CURS_B  = (size_t)N2 * sizeof(int);                // 1.2 MB
    const size_t BSUM_B  = 1024;
    const size_t REQ = H_B + SSRC_B + SVAL_B + CNT_B + OFFS_B + CURS_B + BSUM_B;

    char* w = (char*)d_ws;
    float* h    = (float*)w;            w += H_B;
    int*   sSrc = (int*)w;              w += SSRC_B;
    float* sVal = (float*)w;            w += SVAL_B;
    int*   cnt  = (int*)w;              w += CNT_B;
    int*   offs = (int*)w;              w += OFFS_B;
    int*   curs = (int*)w;              w += CURS_B;

    const int block = 256;

    if (ws_size >= REQ) {
        int* bsums = (int*)w;
        hipMemsetAsync(cnt, 0, CNT_B, stream);
        hipMemsetAsync(curs, 0, CURS_B, stream);

        hist_kernel<<<1024, block, 0, stream>>>(rows, cols, cnt);
        scanA<<<NB, 256, 0, stream>>>(cnt, bsums);
        scanB<<<1, 256, 0, stream>>>(bsums);
        scanC<<<NB, 256, 0, stream>>>(cnt, bsums, offs);
        scatter_build<<<1024, block, 0, stream>>>(rows, cols, vals, offs, curs, sSrc, sVal);

        int ggrid = (N_TOTAL * 32 + block - 1) / block;   // 18750 blocks
        gather1<<<ggrid, block, 0, stream>>>(ego, offs, sSrc, sVal, h);
        gather2_ln<<<ggrid, block, 0, stream>>>(h, offs, sSrc, sVal, ego, gamma, beta, out);
    } else {
        // fallback: atomic scatter (needs only h)
        hipMemsetAsync(h, 0, H_B, stream);
        hipMemsetAsync(out, 0, H_B, stream);
        long total = (long)NNZ_E * 32;
        int grid = (int)((total + block - 1) / block);
        scatter_kernel<<<grid, block, 0, stream>>>(ego, vals, rows, cols, h, NNZ_E);
        scatter_kernel<<<grid, block, 0, stream>>>(h, vals, cols, rows, out, NNZ_E);
        int lngrid = (N_TOTAL * 64 + block - 1) / block;
        ln_residual_kernel<<<lngrid, block, 0, stream>>>(out, ego, gamma, beta, out, N_TOTAL);
    }
}

// Round 3
// 489.325 us; speedup vs baseline: 10.5510x; 1.3582x over previous
//
#include <hip/hip_runtime.h>

#define N_TOTAL 150000
#define DIM 128
#define NNZ_E 1500000
#define NBUCK 256
#define DPB 586                 // dests per bucket: 256*586 = 150016 >= 150000
#define EPB 4096                // edges per phase-A block
#define A_BLOCKS ((NNZ_E + EPB - 1) / EPB)   // 367

// ---------- coarse histogram: 256 buckets per pass, LDS-aggregated ----------
__global__ __launch_bounds__(256) void coarse_hist(const int* __restrict__ rows,
                                                   const int* __restrict__ cols,
                                                   int* __restrict__ cnt1,
                                                   int* __restrict__ cnt2) {
    __shared__ int h[512];
    int t = threadIdx.x;
    h[t] = 0; h[t + 256] = 0;
    __syncthreads();
    int stride = gridDim.x * blockDim.x;
    for (int e = blockIdx.x * blockDim.x + t; e < NNZ_E; e += stride) {
        atomicAdd(&h[cols[e] / DPB], 1);          // pass-1 dest = col
        atomicAdd(&h[256 + rows[e] / DPB], 1);    // pass-2 dest = row
    }
    __syncthreads();
    if (h[t]) atomicAdd(&cnt1[t], h[t]);
    if (h[t + 256]) atomicAdd(&cnt2[t], h[t + 256]);
}

// ---------- scan both 256-bucket counts -> slab bases; zero global cursors ----------
__global__ __launch_bounds__(256) void scan_buckets(const int* __restrict__ cnt1,
                                                    const int* __restrict__ cnt2,
                                                    int* __restrict__ sb1, int* __restrict__ sb2,
                                                    int* __restrict__ gc1, int* __restrict__ gc2) {
    __shared__ int buf[256];
    int t = threadIdx.x;
    int v = cnt1[t]; buf[t] = v; __syncthreads();
    for (int o = 1; o < 256; o <<= 1) {
        int a = (t >= o) ? buf[t - o] : 0; __syncthreads();
        buf[t] += a; __syncthreads();
    }
    sb1[t] = buf[t] - v;
    if (t == 255) sb1[256] = buf[255];
    __syncthreads();
    int v2 = cnt2[t]; buf[t] = v2; __syncthreads();
    for (int o = 1; o < 256; o <<= 1) {
        int a = (t >= o) ? buf[t - o] : 0; __syncthreads();
        buf[t] += a; __syncthreads();
    }
    sb2[t] = buf[t] - v2;
    if (t == 255) sb2[256] = buf[255];
    gc1[t] = 0; gc2[t] = 0;
}

// ---------- phase A: bucket-bin 4096 edges per block in LDS, flush coalesced ----------
__global__ __launch_bounds__(256) void phaseA(const int* __restrict__ dstIdx,
                                              const int* __restrict__ srcIdx,
                                              const float* __restrict__ vals,
                                              const int* __restrict__ slabBase,
                                              int* __restrict__ gCur,
                                              uint2* __restrict__ slab) {
    __shared__ uint2 sortedL[EPB];          // 32 KB
    __shared__ unsigned short bktL[EPB];    // 8 KB
    __shared__ int cnt[NBUCK], off[NBUCK], cur[NBUCK], gbase[NBUCK];
    __shared__ int totE;
    int t = threadIdx.x;
    int base = blockIdx.x * EPB;
    cnt[t] = 0;
    __syncthreads();

    uint2 epk[16];
    short ebk[16];
    #pragma unroll
    for (int j = 0; j < 16; j++) {
        int e = base + j * 256 + t;
        if (e < NNZ_E) {
            int d = dstIdx[e], s = srcIdx[e];
            float v = vals[e];
            int b = d / DPB;
            int dl = d - b * DPB;
            ebk[j] = (short)b;
            epk[j].x = ((unsigned)dl << 18) | (unsigned)s;   // dl<10b, s<18b
            epk[j].y = __float_as_uint(v);
            atomicAdd(&cnt[b], 1);
        } else ebk[j] = -1;
    }
    __syncthreads();
    // inclusive scan of cnt over 256
    int v = cnt[t];
    off[t] = v;
    __syncthreads();
    for (int o = 1; o < 256; o <<= 1) {
        int a = (t >= o) ? off[t - o] : 0; __syncthreads();
        off[t] += a; __syncthreads();
    }
    int excl = off[t] - v;
    if (t == 255) totE = off[255];
    off[t] = excl;      // own element only — safe
    cur[t] = excl;
    __syncthreads();
    // bucket-sorted scatter into LDS
    #pragma unroll
    for (int j = 0; j < 16; j++) {
        if (ebk[j] >= 0) {
            int p = atomicAdd(&cur[(int)ebk[j]], 1);
            sortedL[p] = epk[j];
            bktL[p] = (unsigned short)ebk[j];
        }
    }
    __syncthreads();
    // reserve global slab space, one atomic per non-empty bucket
    int n = cnt[t];
    if (n > 0) gbase[t] = atomicAdd(&gCur[t], n);
    __syncthreads();
    // coalesced-ish flush (consecutive slots -> consecutive global addrs within a run)
    int nE = totE;
    for (int i = t; i < nE; i += 256) {
        int b = bktL[i];
        slab[slabBase[b] + gbase[b] + (i - off[b])] = sortedL[i];
    }
}

// ---------- phase B: per-bucket exact sort + offs write + (src,val) emit ----------
__global__ __launch_bounds__(256) void phaseB(const uint2* __restrict__ slab,
                                              const int* __restrict__ slabBase,
                                              int* __restrict__ offs,
                                              uint2* __restrict__ sorted) {
    __shared__ int cnt[DPB], sc[DPB], cur[DPB], part[256];
    int b = blockIdx.x, t = threadIdx.x;
    int sb = slabBase[b], se = slabBase[b + 1];
    int n = se - sb;
    for (int d = t; d < DPB; d += 256) cnt[d] = 0;
    __syncthreads();
    for (int i = t; i < n; i += 256)
        atomicAdd(&cnt[slab[sb + i].x >> 18], 1);
    __syncthreads();
    // scan DPB bins, 3 per thread
    int d0 = t * 3;
    int c0 = (d0     < DPB) ? cnt[d0]     : 0;
    int c1 = (d0 + 1 < DPB) ? cnt[d0 + 1] : 0;
    int c2 = (d0 + 2 < DPB) ? cnt[d0 + 2] : 0;
    int ps = c0 + c1 + c2;
    part[t] = ps;
    __syncthreads();
    for (int o = 1; o < 256; o <<= 1) {
        int a = (t >= o) ? part[t - o] : 0; __syncthreads();
        part[t] += a; __syncthreads();
    }
    int bs = part[t] - ps;
    if (d0     < DPB) { sc[d0]     = bs;           cur[d0]     = bs; }
    if (d0 + 1 < DPB) { sc[d0 + 1] = bs + c0;      cur[d0 + 1] = bs + c0; }
    if (d0 + 2 < DPB) { sc[d0 + 2] = bs + c0 + c1; cur[d0 + 2] = bs + c0 + c1; }
    __syncthreads();
    // per-dest offsets (global cumulative); dd==N_TOTAL is the sentinel
    int destBase = b * DPB;
    for (int d = t; d < DPB; d += 256) {
        int dd = destBase + d;
        if (dd <= N_TOTAL) offs[dd] = sb + sc[d];
    }
    // emit (src, val) — scatters stay inside this bucket's ~47 KB L2-hot window
    for (int i = t; i < n; i += 256) {
        uint2 e = slab[sb + i];
        int dl = e.x >> 18;
        int p = atomicAdd(&cur[dl], 1);
        sorted[sb + p] = make_uint2(e.x & 0x3FFFF, e.y);
    }
}

// ---------- gather passes: 64 lanes per row, meta broadcast from registers ----------
__global__ __launch_bounds__(256) void gather1(const float* __restrict__ src,
                                               const int* __restrict__ offs,
                                               const uint2* __restrict__ edges,
                                               float* __restrict__ dst) {
    int gid = blockIdx.x * 256 + threadIdx.x;
    int row = gid >> 6, lane = gid & 63;
    if (row >= N_TOTAL) return;
    int beg = offs[row], end = offs[row + 1];
    int n = end - beg;
    uint2 meta = (lane < n) ? edges[beg + lane] : make_uint2(0u, 0u);
    float2 acc = make_float2(0.f, 0.f);
    const float2* s2 = (const float2*)src;
    int nin = n < 64 ? n : 64;
    for (int i = 0; i < nin; i++) {
        int s = __shfl((int)meta.x, i, 64);
        float v = __uint_as_float((unsigned)__shfl((int)meta.y, i, 64));
        float2 x = s2[(size_t)s * 64 + lane];
        acc.x += v * x.x; acc.y += v * x.y;
    }
    for (int i = 64; i < n; i++) {           // statistically never (avg deg 10)
        uint2 e = edges[beg + i];
        float v = __uint_as_float(e.y);
        float2 x = s2[(size_t)e.x * 64 + lane];
        acc.x += v * x.x; acc.y += v * x.y;
    }
    ((float2*)dst)[(size_t)row * 64 + lane] = acc;
}

__global__ __launch_bounds__(256) void gather2_ln(const float* __restrict__ h,
                                                  const int* __restrict__ offs,
                                                  const uint2* __restrict__ edges,
                                                  const float* __restrict__ ego,
                                                  const float* __restrict__ gamma,
                                                  const float* __restrict__ beta,
                                                  float* __restrict__ out) {
    int gid = blockIdx.x * 256 + threadIdx.x;
    int row = gid >> 6, lane = gid & 63;
    if (row >= N_TOTAL) return;
    int beg = offs[N_TOTAL + row] - NNZ_E;   // pass-2 offs are stored NNZ-shifted? no: separate array, see launch
    // NOTE: offs pointer passed already points at pass-2 array; beg/end are slab-relative
    beg = offs[row]; int end = offs[row + 1];
    int n = end - beg;
    uint2 meta = (lane < n) ? edges[beg + lane] : make_uint2(0u, 0u);
    float2 acc = make_float2(0.f, 0.f);
    const float2* s2 = (const float2*)h;
    int nin = n < 64 ? n : 64;
    for (int i = 0; i < nin; i++) {
        int s = __shfl((int)meta.x, i, 64);
        float v = __uint_as_float((unsigned)__shfl((int)meta.y, i, 64));
        float2 x = s2[(size_t)s * 64 + lane];
        acc.x += v * x.x; acc.y += v * x.y;
    }
    for (int i = 64; i < n; i++) {
        uint2 e = edges[beg + i];
        float v = __uint_as_float(e.y);
        float2 x = s2[(size_t)e.x * 64 + lane];
        acc.x += v * x.x; acc.y += v * x.y;
    }
    float s = acc.x + acc.y;
    float sq = acc.x * acc.x + acc.y * acc.y;
    #pragma unroll
    for (int o = 32; o > 0; o >>= 1) {
        s  += __shfl_xor(s, o, 64);
        sq += __shfl_xor(sq, o, 64);
    }
    float mu = s * (1.0f / DIM);
    float var = sq * (1.0f / DIM) - mu * mu;
    float rs = rsqrtf(var + 1e-5f);
    float2 g  = ((const float2*)gamma)[lane];
    float2 bb = ((const float2*)beta)[lane];
    float2 e2 = ((const float2*)ego)[(size_t)row * 64 + lane];
    float2 o2;
    o2.x = (acc.x - mu) * rs * g.x + bb.x + e2.x;
    o2.y = (acc.y - mu) * rs * g.y + bb.y + e2.y;
    ((float2*)out)[(size_t)row * 64 + lane] = o2;
}

// ---------- fallback: atomic scatter path (ws too small) ----------
__device__ __forceinline__ void atomic_add_f32(float* p, float v) {
    __hip_atomic_fetch_add(p, v, __ATOMIC_RELAXED, __HIP_MEMORY_SCOPE_AGENT);
}
__global__ void scatter_kernel(const float* __restrict__ src, const float* __restrict__ vals,
                               const int* __restrict__ gidx, const int* __restrict__ sidx,
                               float* __restrict__ dst, int nnz) {
    int gid = blockIdx.x * blockDim.x + threadIdx.x;
    int e = gid >> 5, lane = gid & 31;
    if (e >= nnz) return;
    float v = vals[e];
    float4 x = ((const float4*)(src + (size_t)gidx[e] * DIM))[lane];
    float* d = dst + (size_t)sidx[e] * DIM + lane * 4;
    atomic_add_f32(d + 0, v * x.x); atomic_add_f32(d + 1, v * x.y);
    atomic_add_f32(d + 2, v * x.z); atomic_add_f32(d + 3, v * x.w);
}
__global__ void ln_residual_kernel(const float* __restrict__ h2, const float* __restrict__ ego,
                                   const float* __restrict__ gamma, const float* __restrict__ beta,
                                   float* __restrict__ out, int nrows) {
    int gid = blockIdx.x * blockDim.x + threadIdx.x;
    int row = gid >> 6, lane = gid & 63;
    if (row >= nrows) return;
    float2 x = ((const float2*)(h2 + (size_t)row * DIM))[lane];
    float s = x.x + x.y, sq = x.x * x.x + x.y * x.y;
    #pragma unroll
    for (int o = 32; o > 0; o >>= 1) { s += __shfl_xor(s, o, 64); sq += __shfl_xor(sq, o, 64); }
    float mu = s * (1.0f / DIM), var = sq * (1.0f / DIM) - mu * mu;
    float rs = rsqrtf(var + 1e-5f);
    float2 eg = ((const float2*)(ego + (size_t)row * DIM))[lane];
    float2 g = ((const float2*)gamma)[lane], b = ((const float2*)beta)[lane];
    float2 o2;
    o2.x = (x.x - mu) * rs * g.x + b.x + eg.x;
    o2.y = (x.y - mu) * rs * g.y + b.y + eg.y;
    ((float2*)(out + (size_t)row * DIM))[lane] = o2;
}

// ---------- launch ----------
extern "C" void kernel_launch(void* const* d_in, const int* in_sizes, int n_in,
                              void* d_out, int out_size, void* d_ws, size_t ws_size,
                              hipStream_t stream) {
    const float* ego   = (const float*)d_in[0];
    const float* vals  = (const float*)d_in[1];
    const float* gamma = (const float*)d_in[2];
    const float* beta  = (const float*)d_in[3];
    const int*   rows  = (const int*)d_in[4];
    const int*   cols  = (const int*)d_in[5];
    float* out = (float*)d_out;

    const size_t H_B    = (size_t)N_TOTAL * DIM * sizeof(float);   // 76.8 MB
    const size_t SLAB_B = (size_t)NNZ_E * sizeof(uint2);           // 12 MB
    const size_t SORT_B = (size_t)NNZ_E * sizeof(uint2);           // 12 MB
    const size_t OFFS_B = ((size_t)N_TOTAL + 16) * sizeof(int);    // ~0.6 MB each
    const size_t SMALL  = 8192;
    const size_t REQ = H_B + SLAB_B + SORT_B + 2 * OFFS_B + SMALL;

    char* w = (char*)d_ws;
    float* h      = (float*)w;  w += H_B;
    uint2* slab   = (uint2*)w;  w += SLAB_B;
    uint2* sorted = (uint2*)w;  w += SORT_B;
    int* offs1    = (int*)w;    w += OFFS_B;
    int* offs2    = (int*)w;    w += OFFS_B;
    int* cnt1     = (int*)w;    w += NBUCK * sizeof(int);
    int* cnt2     = (int*)w;    w += NBUCK * sizeof(int);
    int* sb1      = (int*)w;    w += (NBUCK + 1) * sizeof(int);
    int* sb2      = (int*)w;    w += (NBUCK + 1) * sizeof(int);
    int* gc1      = (int*)w;    w += NBUCK * sizeof(int);
    int* gc2      = (int*)w;    w += NBUCK * sizeof(int);

    if (ws_size >= REQ) {
        hipMemsetAsync(cnt1, 0, 2 * NBUCK * sizeof(int), stream);
        coarse_hist<<<512, 256, 0, stream>>>(rows, cols, cnt1, cnt2);
        scan_buckets<<<1, 256, 0, stream>>>(cnt1, cnt2, sb1, sb2, gc1, gc2);

        int ggrid = (N_TOTAL * 64) / 256;   // 37500
        // pass 1: dest=col, src=row
        phaseA<<<A_BLOCKS, 256, 0, stream>>>(cols, rows, vals, sb1, gc1, slab);
        phaseB<<<NBUCK, 256, 0, stream>>>(slab, sb1, offs1, sorted);
        gather1<<<ggrid, 256, 0, stream>>>(ego, offs1, sorted, h);
        // pass 2: dest=row, src=col
        phaseA<<<A_BLOCKS, 256, 0, stream>>>(rows, cols, vals, sb2, gc2, slab);
        phaseB<<<NBUCK, 256, 0, stream>>>(slab, sb2, offs2, sorted);
        gather2_ln<<<ggrid, 256, 0, stream>>>(h, offs2, sorted, ego, gamma, beta, out);
    } else {
        hipMemsetAsync(h, 0, H_B, stream);
        hipMemsetAsync(out, 0, H_B, stream);
        long total = (long)NNZ_E * 32;
        int grid = (int)((total + 255) / 256);
        scatter_kernel<<<grid, 256, 0, stream>>>(ego, vals, rows, cols, h, NNZ_E);
        scatter_kernel<<<grid, 256, 0, stream>>>(h, vals, cols, rows, out, NNZ_E);
        int lngrid = (N_TOTAL * 64 + 255) / 256;
        ln_residual_kernel<<<lngrid, 256, 0, stream>>>(out, ego, gamma, beta, out, N_TOTAL);
    }
}

// Round 4
// 465.942 us; speedup vs baseline: 11.0805x; 1.0502x over previous
//
#include <hip/hip_runtime.h>

#define N_TOTAL 150000
#define DIM 128
#define NNZ_E 1500000
#define NBUCK 256
#define DPB 586                 // dests per bucket: 256*586 = 150016 >= 150000
#define EPB 4096                // edges per phase-A block
#define A_BLOCKS ((NNZ_E + EPB - 1) / EPB)   // 367

// ---------- bf16 pack/unpack (RNE) ----------
__device__ __forceinline__ unsigned pack_bf16(float a, float b) {
    unsigned ua = __float_as_uint(a), ub = __float_as_uint(b);
    ua = (ua + 0x7FFFu + ((ua >> 16) & 1u)) >> 16;
    ub = (ub + 0x7FFFu + ((ub >> 16) & 1u)) >> 16;
    return ua | (ub << 16);
}
__device__ __forceinline__ float2 unpack_bf16(unsigned u) {
    return make_float2(__uint_as_float(u << 16), __uint_as_float(u & 0xFFFF0000u));
}

// ---------- ego fp32 -> packed bf16 ----------
__global__ __launch_bounds__(256) void conv_bf16(const float* __restrict__ in,
                                                 uint* __restrict__ outp) {
    int i = blockIdx.x * 256 + threadIdx.x;      // exactly N*D/8 threads
    const float4* in4 = (const float4*)in;
    float4 a = in4[2 * i], b = in4[2 * i + 1];
    uint4 o;
    o.x = pack_bf16(a.x, a.y);
    o.y = pack_bf16(a.z, a.w);
    o.z = pack_bf16(b.x, b.y);
    o.w = pack_bf16(b.z, b.w);
    ((uint4*)outp)[i] = o;
}

// ---------- coarse histogram: 256 buckets per pass, LDS-aggregated ----------
__global__ __launch_bounds__(256) void coarse_hist(const int* __restrict__ rows,
                                                   const int* __restrict__ cols,
                                                   int* __restrict__ cnt1,
                                                   int* __restrict__ cnt2) {
    __shared__ int h[512];
    int t = threadIdx.x;
    h[t] = 0; h[t + 256] = 0;
    __syncthreads();
    int stride = gridDim.x * blockDim.x;
    for (int e = blockIdx.x * blockDim.x + t; e < NNZ_E; e += stride) {
        atomicAdd(&h[cols[e] / DPB], 1);
        atomicAdd(&h[256 + rows[e] / DPB], 1);
    }
    __syncthreads();
    if (h[t]) atomicAdd(&cnt1[t], h[t]);
    if (h[t + 256]) atomicAdd(&cnt2[t], h[t + 256]);
}

// ---------- scan bucket counts -> slab bases; zero cursors ----------
__global__ __launch_bounds__(256) void scan_buckets(const int* __restrict__ cnt1,
                                                    const int* __restrict__ cnt2,
                                                    int* __restrict__ sb1, int* __restrict__ sb2,
                                                    int* __restrict__ gc1, int* __restrict__ gc2) {
    __shared__ int buf[256];
    int t = threadIdx.x;
    int v = cnt1[t]; buf[t] = v; __syncthreads();
    for (int o = 1; o < 256; o <<= 1) {
        int a = (t >= o) ? buf[t - o] : 0; __syncthreads();
        buf[t] += a; __syncthreads();
    }
    sb1[t] = buf[t] - v;
    if (t == 255) sb1[256] = buf[255];
    __syncthreads();
    int v2 = cnt2[t]; buf[t] = v2; __syncthreads();
    for (int o = 1; o < 256; o <<= 1) {
        int a = (t >= o) ? buf[t - o] : 0; __syncthreads();
        buf[t] += a; __syncthreads();
    }
    sb2[t] = buf[t] - v2;
    if (t == 255) sb2[256] = buf[255];
    gc1[t] = 0; gc2[t] = 0;
}

// ---------- phase A: bucket-bin 4096 edges per block in LDS, flush coalesced ----------
__global__ __launch_bounds__(256) void phaseA(const int* __restrict__ dstIdx,
                                              const int* __restrict__ srcIdx,
                                              const float* __restrict__ vals,
                                              const int* __restrict__ slabBase,
                                              int* __restrict__ gCur,
                                              uint2* __restrict__ slab) {
    __shared__ uint2 sortedL[EPB];          // 32 KB
    __shared__ unsigned short bktL[EPB];    // 8 KB
    __shared__ int cnt[NBUCK], off[NBUCK], cur[NBUCK], gbase[NBUCK];
    __shared__ int totE;
    int t = threadIdx.x;
    int base = blockIdx.x * EPB;
    cnt[t] = 0;
    __syncthreads();

    uint2 epk[16];
    short ebk[16];
    #pragma unroll
    for (int j = 0; j < 16; j++) {
        int e = base + j * 256 + t;
        if (e < NNZ_E) {
            int d = dstIdx[e], s = srcIdx[e];
            float v = vals[e];
            int b = d / DPB;
            int dl = d - b * DPB;
            ebk[j] = (short)b;
            epk[j].x = ((unsigned)dl << 18) | (unsigned)s;
            epk[j].y = __float_as_uint(v);
            atomicAdd(&cnt[b], 1);
        } else ebk[j] = -1;
    }
    __syncthreads();
    int v = cnt[t];
    off[t] = v;
    __syncthreads();
    for (int o = 1; o < 256; o <<= 1) {
        int a = (t >= o) ? off[t - o] : 0; __syncthreads();
        off[t] += a; __syncthreads();
    }
    int excl = off[t] - v;
    if (t == 255) totE = off[255];
    off[t] = excl;
    cur[t] = excl;
    __syncthreads();
    #pragma unroll
    for (int j = 0; j < 16; j++) {
        if (ebk[j] >= 0) {
            int p = atomicAdd(&cur[(int)ebk[j]], 1);
            sortedL[p] = epk[j];
            bktL[p] = (unsigned short)ebk[j];
        }
    }
    __syncthreads();
    int n = cnt[t];
    if (n > 0) gbase[t] = atomicAdd(&gCur[t], n);
    __syncthreads();
    int nE = totE;
    for (int i = t; i < nE; i += 256) {
        int b = bktL[i];
        slab[slabBase[b] + gbase[b] + (i - off[b])] = sortedL[i];
    }
}

// ---------- phase B: per-bucket exact sort + offs write + (src,val) emit ----------
__global__ __launch_bounds__(256) void phaseB(const uint2* __restrict__ slab,
                                              const int* __restrict__ slabBase,
                                              int* __restrict__ offs,
                                              uint2* __restrict__ sorted) {
    __shared__ int cnt[DPB], sc[DPB], cur[DPB], part[256];
    int b = blockIdx.x, t = threadIdx.x;
    int sb = slabBase[b], se = slabBase[b + 1];
    int n = se - sb;
    for (int d = t; d < DPB; d += 256) cnt[d] = 0;
    __syncthreads();
    for (int i = t; i < n; i += 256)
        atomicAdd(&cnt[slab[sb + i].x >> 18], 1);
    __syncthreads();
    int d0 = t * 3;
    int c0 = (d0     < DPB) ? cnt[d0]     : 0;
    int c1 = (d0 + 1 < DPB) ? cnt[d0 + 1] : 0;
    int c2 = (d0 + 2 < DPB) ? cnt[d0 + 2] : 0;
    int ps = c0 + c1 + c2;
    part[t] = ps;
    __syncthreads();
    for (int o = 1; o < 256; o <<= 1) {
        int a = (t >= o) ? part[t - o] : 0; __syncthreads();
        part[t] += a; __syncthreads();
    }
    int bs = part[t] - ps;
    if (d0     < DPB) { sc[d0]     = bs;           cur[d0]     = bs; }
    if (d0 + 1 < DPB) { sc[d0 + 1] = bs + c0;      cur[d0 + 1] = bs + c0; }
    if (d0 + 2 < DPB) { sc[d0 + 2] = bs + c0 + c1; cur[d0 + 2] = bs + c0 + c1; }
    __syncthreads();
    int destBase = b * DPB;
    for (int d = t; d < DPB; d += 256) {
        int dd = destBase + d;
        if (dd <= N_TOTAL) offs[dd] = sb + sc[d];
    }
    for (int i = t; i < n; i += 256) {
        uint2 e = slab[sb + i];
        int dl = e.x >> 18;
        int p = atomicAdd(&cur[dl], 1);
        sorted[sb + p] = make_uint2(e.x & 0x3FFFF, e.y);
    }
}

// ---------- gather 1: bf16 in, bf16 out ----------
__global__ __launch_bounds__(256) void gather1(const uint* __restrict__ srcBf,
                                               const int* __restrict__ offs,
                                               const uint2* __restrict__ edges,
                                               uint* __restrict__ dstBf) {
    int gid = blockIdx.x * 256 + threadIdx.x;
    int row = gid >> 6, lane = gid & 63;
    if (row >= N_TOTAL) return;
    int beg = offs[row], end = offs[row + 1];
    int n = end - beg;
    uint2 meta = (lane < n) ? edges[beg + lane] : make_uint2(0u, 0u);
    float2 acc = make_float2(0.f, 0.f);
    int nin = n < 64 ? n : 64;
    for (int i = 0; i < nin; i++) {
        int s = __shfl((int)meta.x, i, 64);
        float v = __uint_as_float((unsigned)__shfl((int)meta.y, i, 64));
        float2 x = unpack_bf16(srcBf[(size_t)s * 64 + lane]);
        acc.x += v * x.x; acc.y += v * x.y;
    }
    for (int i = 64; i < n; i++) {
        uint2 e = edges[beg + i];
        float v = __uint_as_float(e.y);
        float2 x = unpack_bf16(srcBf[(size_t)e.x * 64 + lane]);
        acc.x += v * x.x; acc.y += v * x.y;
    }
    dstBf[(size_t)row * 64 + lane] = pack_bf16(acc.x, acc.y);
}

// ---------- gather 2 + LN + residual: bf16 in, fp32 out ----------
__global__ __launch_bounds__(256) void gather2_ln(const uint* __restrict__ hBf,
                                                  const int* __restrict__ offs,
                                                  const uint2* __restrict__ edges,
                                                  const uint* __restrict__ egoBf,
                                                  const float* __restrict__ gamma,
                                                  const float* __restrict__ beta,
                                                  float* __restrict__ out) {
    int gid = blockIdx.x * 256 + threadIdx.x;
    int row = gid >> 6, lane = gid & 63;
    if (row >= N_TOTAL) return;
    int beg = offs[row], end = offs[row + 1];
    int n = end - beg;
    uint2 meta = (lane < n) ? edges[beg + lane] : make_uint2(0u, 0u);
    float2 acc = make_float2(0.f, 0.f);
    int nin = n < 64 ? n : 64;
    for (int i = 0; i < nin; i++) {
        int s = __shfl((int)meta.x, i, 64);
        float v = __uint_as_float((unsigned)__shfl((int)meta.y, i, 64));
        float2 x = unpack_bf16(hBf[(size_t)s * 64 + lane]);
        acc.x += v * x.x; acc.y += v * x.y;
    }
    for (int i = 64; i < n; i++) {
        uint2 e = edges[beg + i];
        float v = __uint_as_float(e.y);
        float2 x = unpack_bf16(hBf[(size_t)e.x * 64 + lane]);
        acc.x += v * x.x; acc.y += v * x.y;
    }
    float s = acc.x + acc.y;
    float sq = acc.x * acc.x + acc.y * acc.y;
    #pragma unroll
    for (int o = 32; o > 0; o >>= 1) {
        s  += __shfl_xor(s, o, 64);
        sq += __shfl_xor(sq, o, 64);
    }
    float mu = s * (1.0f / DIM);
    float var = sq * (1.0f / DIM) - mu * mu;
    float rs = rsqrtf(var + 1e-5f);
    float2 g  = ((const float2*)gamma)[lane];
    float2 bb = ((const float2*)beta)[lane];
    float2 e2 = unpack_bf16(egoBf[(size_t)row * 64 + lane]);
    float2 o2;
    o2.x = (acc.x - mu) * rs * g.x + bb.x + e2.x;
    o2.y = (acc.y - mu) * rs * g.y + bb.y + e2.y;
    ((float2*)out)[(size_t)row * 64 + lane] = o2;
}

// ---------- fallback: atomic scatter path (ws too small) ----------
__device__ __forceinline__ void atomic_add_f32(float* p, float v) {
    __hip_atomic_fetch_add(p, v, __ATOMIC_RELAXED, __HIP_MEMORY_SCOPE_AGENT);
}
__global__ void scatter_kernel(const float* __restrict__ src, const float* __restrict__ vals,
                               const int* __restrict__ gidx, const int* __restrict__ sidx,
                               float* __restrict__ dst, int nnz) {
    int gid = blockIdx.x * blockDim.x + threadIdx.x;
    int e = gid >> 5, lane = gid & 31;
    if (e >= nnz) return;
    float v = vals[e];
    float4 x = ((const float4*)(src + (size_t)gidx[e] * DIM))[lane];
    float* d = dst + (size_t)sidx[e] * DIM + lane * 4;
    atomic_add_f32(d + 0, v * x.x); atomic_add_f32(d + 1, v * x.y);
    atomic_add_f32(d + 2, v * x.z); atomic_add_f32(d + 3, v * x.w);
}
__global__ void ln_residual_kernel(const float* __restrict__ h2, const float* __restrict__ ego,
                                   const float* __restrict__ gamma, const float* __restrict__ beta,
                                   float* __restrict__ out, int nrows) {
    int gid = blockIdx.x * blockDim.x + threadIdx.x;
    int row = gid >> 6, lane = gid & 63;
    if (row >= nrows) return;
    float2 x = ((const float2*)(h2 + (size_t)row * DIM))[lane];
    float s = x.x + x.y, sq = x.x * x.x + x.y * x.y;
    #pragma unroll
    for (int o = 32; o > 0; o >>= 1) { s += __shfl_xor(s, o, 64); sq += __shfl_xor(sq, o, 64); }
    float mu = s * (1.0f / DIM), var = sq * (1.0f / DIM) - mu * mu;
    float rs = rsqrtf(var + 1e-5f);
    float2 eg = ((const float2*)(ego + (size_t)row * DIM))[lane];
    float2 g = ((const float2*)gamma)[lane], b = ((const float2*)beta)[lane];
    float2 o2;
    o2.x = (x.x - mu) * rs * g.x + b.x + eg.x;
    o2.y = (x.y - mu) * rs * g.y + b.y + eg.y;
    ((float2*)(out + (size_t)row * DIM))[lane] = o2;
}

// ---------- launch ----------
extern "C" void kernel_launch(void* const* d_in, const int* in_sizes, int n_in,
                              void* d_out, int out_size, void* d_ws, size_t ws_size,
                              hipStream_t stream) {
    const float* ego   = (const float*)d_in[0];
    const float* vals  = (const float*)d_in[1];
    const float* gamma = (const float*)d_in[2];
    const float* beta  = (const float*)d_in[3];
    const int*   rows  = (const int*)d_in[4];
    const int*   cols  = (const int*)d_in[5];
    float* out = (float*)d_out;

    const size_t EGO_BF_B = (size_t)N_TOTAL * DIM * 2;             // 38.4 MB
    const size_t H_BF_B   = (size_t)N_TOTAL * DIM * 2;             // 38.4 MB
    const size_t SLAB_B   = (size_t)NNZ_E * sizeof(uint2);         // 12 MB
    const size_t SORT_B   = (size_t)NNZ_E * sizeof(uint2);         // 12 MB
    const size_t OFFS_B   = ((size_t)N_TOTAL + 16) * sizeof(int);  // ~0.6 MB each
    const size_t SMALL    = 8192;
    const size_t REQ = EGO_BF_B + H_BF_B + SLAB_B + SORT_B + 2 * OFFS_B + SMALL;
    const size_t H_FP32_B = (size_t)N_TOTAL * DIM * sizeof(float); // fallback: 76.8 MB

    char* w = (char*)d_ws;
    uint* egoBf   = (uint*)w;   w += EGO_BF_B;
    uint* hBf     = (uint*)w;   w += H_BF_B;
    uint2* slab   = (uint2*)w;  w += SLAB_B;
    uint2* sorted = (uint2*)w;  w += SORT_B;
    int* offs1    = (int*)w;    w += OFFS_B;
    int* offs2    = (int*)w;    w += OFFS_B;
    int* cnt1     = (int*)w;    w += NBUCK * sizeof(int);
    int* cnt2     = (int*)w;    w += NBUCK * sizeof(int);
    int* sb1      = (int*)w;    w += (NBUCK + 1) * sizeof(int);
    int* sb2      = (int*)w;    w += (NBUCK + 1) * sizeof(int);
    int* gc1      = (int*)w;    w += NBUCK * sizeof(int);
    int* gc2      = (int*)w;    w += NBUCK * sizeof(int);

    if (ws_size >= REQ) {
        hipMemsetAsync(cnt1, 0, 2 * NBUCK * sizeof(int), stream);
        conv_bf16<<<(N_TOTAL * DIM / 8) / 256, 256, 0, stream>>>(ego, egoBf);
        coarse_hist<<<512, 256, 0, stream>>>(rows, cols, cnt1, cnt2);
        scan_buckets<<<1, 256, 0, stream>>>(cnt1, cnt2, sb1, sb2, gc1, gc2);

        int ggrid = (N_TOTAL * 64) / 256;   // 37500
        // pass 1: dest=col, src=row
        phaseA<<<A_BLOCKS, 256, 0, stream>>>(cols, rows, vals, sb1, gc1, slab);
        phaseB<<<NBUCK, 256, 0, stream>>>(slab, sb1, offs1, sorted);
        gather1<<<ggrid, 256, 0, stream>>>(egoBf, offs1, sorted, hBf);
        // pass 2: dest=row, src=col
        phaseA<<<A_BLOCKS, 256, 0, stream>>>(rows, cols, vals, sb2, gc2, slab);
        phaseB<<<NBUCK, 256, 0, stream>>>(slab, sb2, offs2, sorted);
        gather2_ln<<<ggrid, 256, 0, stream>>>(hBf, offs2, sorted, egoBf, gamma, beta, out);
    } else {
        float* h = (float*)d_ws;            // fallback: fp32 h at ws start
        hipMemsetAsync(h, 0, H_FP32_B, stream);
        hipMemsetAsync(out, 0, H_FP32_B, stream);
        long total = (long)NNZ_E * 32;
        int grid = (int)((total + 255) / 256);
        scatter_kernel<<<grid, 256, 0, stream>>>(ego, vals, rows, cols, h, NNZ_E);
        scatter_kernel<<<grid, 256, 0, stream>>>(h, vals, cols, rows, out, NNZ_E);
        int lngrid = (N_TOTAL * 64 + 255) / 256;
        ln_residual_kernel<<<lngrid, 256, 0, stream>>>(out, ego, gamma, beta, out, N_TOTAL);
    }
}

// Round 5
// 385.967 us; speedup vs baseline: 13.3764x; 1.2072x over previous
//
#include <hip/hip_runtime.h>

#define N_TOTAL 150000
#define DIM 128
#define NNZ_E 1500000
#define NBUCK 256
#define DPB 586                 // dests per bucket: 256*586 = 150016 >= 150000
#define EPB2 2048               // edges per fused phase-A block (emits 2 entries each)
#define A2_BLOCKS ((NNZ_E + EPB2 - 1) / EPB2)   // 733

// ---------- bf16 pack/unpack (RNE) ----------
__device__ __forceinline__ unsigned pack_bf16(float a, float b) {
    unsigned ua = __float_as_uint(a), ub = __float_as_uint(b);
    ua = (ua + 0x7FFFu + ((ua >> 16) & 1u)) >> 16;
    ub = (ub + 0x7FFFu + ((ub >> 16) & 1u)) >> 16;
    return ua | (ub << 16);
}
__device__ __forceinline__ float2 unpack_bf16(unsigned u) {
    return make_float2(__uint_as_float(u << 16), __uint_as_float(u & 0xFFFF0000u));
}

// ---------- ego fp32 -> packed bf16 ----------
__global__ __launch_bounds__(256) void conv_bf16(const float* __restrict__ in,
                                                 uint* __restrict__ outp) {
    int i = blockIdx.x * 256 + threadIdx.x;      // exactly N*D/8 threads
    const float4* in4 = (const float4*)in;
    float4 a = in4[2 * i], b = in4[2 * i + 1];
    uint4 o;
    o.x = pack_bf16(a.x, a.y);
    o.y = pack_bf16(a.z, a.w);
    o.z = pack_bf16(b.x, b.y);
    o.w = pack_bf16(b.z, b.w);
    ((uint4*)outp)[i] = o;
}

// ---------- coarse histogram: 2x256 buckets, LDS-aggregated ----------
__global__ __launch_bounds__(256) void coarse_hist(const int* __restrict__ rows,
                                                   const int* __restrict__ cols,
                                                   int* __restrict__ cnt1,
                                                   int* __restrict__ cnt2) {
    __shared__ int h[512];
    int t = threadIdx.x;
    h[t] = 0; h[t + 256] = 0;
    __syncthreads();
    int stride = gridDim.x * blockDim.x;
    for (int e = blockIdx.x * blockDim.x + t; e < NNZ_E; e += stride) {
        atomicAdd(&h[cols[e] / DPB], 1);          // pass-1 dest = col
        atomicAdd(&h[256 + rows[e] / DPB], 1);    // pass-2 dest = row
    }
    __syncthreads();
    if (h[t]) atomicAdd(&cnt1[t], h[t]);
    if (h[t + 256]) atomicAdd(&cnt2[t], h[t + 256]);
}

// ---------- scan 512 bucket counts -> slab bases sb[513]; zero cursors ----------
__global__ __launch_bounds__(256) void scan_buckets(const int* __restrict__ cnt,
                                                    int* __restrict__ sb,
                                                    int* __restrict__ gc) {
    __shared__ int buf[256];
    int t = threadIdx.x;
    int v = cnt[t]; buf[t] = v; __syncthreads();
    for (int o = 1; o < 256; o <<= 1) {
        int a = (t >= o) ? buf[t - o] : 0; __syncthreads();
        buf[t] += a; __syncthreads();
    }
    sb[t] = buf[t] - v;               // pass-1 region: [0, NNZ)
    __syncthreads();
    int v2 = cnt[256 + t]; buf[t] = v2; __syncthreads();
    for (int o = 1; o < 256; o <<= 1) {
        int a = (t >= o) ? buf[t - o] : 0; __syncthreads();
        buf[t] += a; __syncthreads();
    }
    sb[256 + t] = NNZ_E + buf[t] - v2;  // pass-2 region: [NNZ, 2*NNZ)
    if (t == 255) sb[512] = 2 * NNZ_E;
    gc[t] = 0; gc[256 + t] = 0;
}

// ---------- fused phase A: bin 2048 edges -> 4096 entries over 512 buckets ----------
__global__ __launch_bounds__(256) void phaseA_fused(const int* __restrict__ rows,
                                                    const int* __restrict__ cols,
                                                    const float* __restrict__ vals,
                                                    const int* __restrict__ slabBase,
                                                    int* __restrict__ gCur,
                                                    uint2* __restrict__ slab) {
    __shared__ uint2 sortedL[2 * EPB2];          // 32 KB
    __shared__ unsigned short bktL[2 * EPB2];    // 8 KB
    __shared__ int cnt[512], off[512], cur[512], gbase[512];   // 8 KB
    __shared__ int part[256];                    // 1 KB
    __shared__ int totE;
    int t = threadIdx.x;
    int base = blockIdx.x * EPB2;
    cnt[t] = 0; cnt[t + 256] = 0;
    __syncthreads();

    uint2 eA[8], eB[8];
    short bA[8], bB[8];
    #pragma unroll
    for (int j = 0; j < 8; j++) {
        int e = base + j * 256 + t;
        if (e < NNZ_E) {
            int r = rows[e], c = cols[e];
            unsigned v = __float_as_uint(vals[e]);
            int b1 = c / DPB, dl1 = c - b1 * DPB;     // pass-1 dest = col, src = row
            int b2 = r / DPB, dl2 = r - b2 * DPB;     // pass-2 dest = row, src = col
            bA[j] = (short)b1;
            eA[j].x = ((unsigned)dl1 << 18) | (unsigned)r;
            eA[j].y = v;
            bB[j] = (short)(256 + b2);
            eB[j].x = ((unsigned)dl2 << 18) | (unsigned)c;
            eB[j].y = v;
            atomicAdd(&cnt[b1], 1);
            atomicAdd(&cnt[256 + b2], 1);
        } else { bA[j] = -1; bB[j] = -1; }
    }
    __syncthreads();
    // scan 512 counts (2 per thread) -> exclusive off/cur
    int c0 = cnt[2 * t], c1 = cnt[2 * t + 1];
    int ps = c0 + c1;
    part[t] = ps; __syncthreads();
    for (int o = 1; o < 256; o <<= 1) {
        int a = (t >= o) ? part[t - o] : 0; __syncthreads();
        part[t] += a; __syncthreads();
    }
    int bs = part[t] - ps;
    off[2 * t] = bs;          cur[2 * t] = bs;
    off[2 * t + 1] = bs + c0; cur[2 * t + 1] = bs + c0;
    if (t == 255) totE = part[255];
    __syncthreads();
    // bucket-sorted scatter into LDS (both entries per edge)
    #pragma unroll
    for (int j = 0; j < 8; j++) {
        if (bA[j] >= 0) {
            int p = atomicAdd(&cur[(int)bA[j]], 1);
            sortedL[p] = eA[j]; bktL[p] = (unsigned short)bA[j];
            p = atomicAdd(&cur[(int)bB[j]], 1);
            sortedL[p] = eB[j]; bktL[p] = (unsigned short)bB[j];
        }
    }
    __syncthreads();
    // reserve global slab space, one atomic per non-empty bucket
    for (int b = t; b < 512; b += 256) {
        int n = cnt[b];
        if (n > 0) gbase[b] = atomicAdd(&gCur[b], n);
    }
    __syncthreads();
    int nE = totE;
    for (int i = t; i < nE; i += 256) {
        int b = bktL[i];
        slab[slabBase[b] + gbase[b] + (i - off[b])] = sortedL[i];
    }
}

// ---------- phase B: per-bucket exact sort + offs write + (src,val) emit ----------
__global__ __launch_bounds__(256) void phaseB(const uint2* __restrict__ slab,
                                              const int* __restrict__ slabBase,
                                              int* __restrict__ offs1,
                                              int* __restrict__ offs2,
                                              uint2* __restrict__ sorted) {
    __shared__ int cnt[DPB], sc[DPB], cur[DPB], part[256];
    int b = blockIdx.x, t = threadIdx.x;
    int sb = slabBase[b], se = slabBase[b + 1];
    int n = se - sb;
    for (int d = t; d < DPB; d += 256) cnt[d] = 0;
    __syncthreads();
    for (int i = t; i < n; i += 256)
        atomicAdd(&cnt[slab[sb + i].x >> 18], 1);
    __syncthreads();
    int d0 = t * 3;
    int c0 = (d0     < DPB) ? cnt[d0]     : 0;
    int c1 = (d0 + 1 < DPB) ? cnt[d0 + 1] : 0;
    int c2 = (d0 + 2 < DPB) ? cnt[d0 + 2] : 0;
    int ps = c0 + c1 + c2;
    part[t] = ps;
    __syncthreads();
    for (int o = 1; o < 256; o <<= 1) {
        int a = (t >= o) ? part[t - o] : 0; __syncthreads();
        part[t] += a; __syncthreads();
    }
    int bs = part[t] - ps;
    if (d0     < DPB) { sc[d0]     = bs;           cur[d0]     = bs; }
    if (d0 + 1 < DPB) { sc[d0 + 1] = bs + c0;      cur[d0 + 1] = bs + c0; }
    if (d0 + 2 < DPB) { sc[d0 + 2] = bs + c0 + c1; cur[d0 + 2] = bs + c0 + c1; }
    __syncthreads();
    int destBase = (b & 255) * DPB;
    int* offs = (b < NBUCK) ? offs1 : offs2;
    for (int d = t; d < DPB; d += 256) {
        int dd = destBase + d;
        if (dd <= N_TOTAL) offs[dd] = sb + sc[d];   // absolute index into sorted[]
    }
    for (int i = t; i < n; i += 256) {
        uint2 e = slab[sb + i];
        int dl = e.x >> 18;
        int p = atomicAdd(&cur[dl], 1);
        sorted[sb + p] = make_uint2(e.x & 0x3FFFF, e.y);
    }
}

// ---------- gather 1: bf16 in, bf16 out, unroll-4 ----------
__global__ __launch_bounds__(256) void gather1(const uint* __restrict__ srcBf,
                                               const int* __restrict__ offs,
                                               const uint2* __restrict__ edges,
                                               uint* __restrict__ dstBf) {
    int gid = blockIdx.x * 256 + threadIdx.x;
    int row = gid >> 6, lane = gid & 63;
    if (row >= N_TOTAL) return;
    int beg = offs[row], end = offs[row + 1];
    int n = end - beg;
    uint2 meta = (lane < n) ? edges[beg + lane] : make_uint2(0u, 0u);
    float2 a0 = make_float2(0.f, 0.f), a1 = make_float2(0.f, 0.f);
    const uint* sp = srcBf + lane;
    int nin = n < 64 ? n : 64;
    int i = 0;
    for (; i + 4 <= nin; i += 4) {
        int s0 = __shfl((int)meta.x, i,     64);
        int s1 = __shfl((int)meta.x, i + 1, 64);
        int s2 = __shfl((int)meta.x, i + 2, 64);
        int s3 = __shfl((int)meta.x, i + 3, 64);
        unsigned x0 = sp[(size_t)s0 << 6];
        unsigned x1 = sp[(size_t)s1 << 6];
        unsigned x2 = sp[(size_t)s2 << 6];
        unsigned x3 = sp[(size_t)s3 << 6];
        float v0 = __uint_as_float((unsigned)__shfl((int)meta.y, i,     64));
        float v1 = __uint_as_float((unsigned)__shfl((int)meta.y, i + 1, 64));
        float v2 = __uint_as_float((unsigned)__shfl((int)meta.y, i + 2, 64));
        float v3 = __uint_as_float((unsigned)__shfl((int)meta.y, i + 3, 64));
        float2 u;
        u = unpack_bf16(x0); a0.x += v0 * u.x; a0.y += v0 * u.y;
        u = unpack_bf16(x1); a1.x += v1 * u.x; a1.y += v1 * u.y;
        u = unpack_bf16(x2); a0.x += v2 * u.x; a0.y += v2 * u.y;
        u = unpack_bf16(x3); a1.x += v3 * u.x; a1.y += v3 * u.y;
    }
    for (; i < nin; i++) {
        int s = __shfl((int)meta.x, i, 64);
        float v = __uint_as_float((unsigned)__shfl((int)meta.y, i, 64));
        float2 u = unpack_bf16(sp[(size_t)s << 6]);
        a0.x += v * u.x; a0.y += v * u.y;
    }
    for (int k = 64; k < n; k++) {       // statistically never (Poisson(10))
        uint2 e = edges[beg + k];
        float v = __uint_as_float(e.y);
        float2 u = unpack_bf16(sp[(size_t)e.x << 6]);
        a0.x += v * u.x; a0.y += v * u.y;
    }
    dstBf[(size_t)row * 64 + lane] = pack_bf16(a0.x + a1.x, a0.y + a1.y);
}

// ---------- gather 2 + LN + residual: bf16 in, fp32 out, unroll-4 ----------
__global__ __launch_bounds__(256) void gather2_ln(const uint* __restrict__ hBf,
                                                  const int* __restrict__ offs,
                                                  const uint2* __restrict__ edges,
                                                  const uint* __restrict__ egoBf,
                                                  const float* __restrict__ gamma,
                                                  const float* __restrict__ beta,
                                                  float* __restrict__ out) {
    int gid = blockIdx.x * 256 + threadIdx.x;
    int row = gid >> 6, lane = gid & 63;
    if (row >= N_TOTAL) return;
    int beg = offs[row], end = offs[row + 1];
    int n = end - beg;
    uint2 meta = (lane < n) ? edges[beg + lane] : make_uint2(0u, 0u);
    float2 a0 = make_float2(0.f, 0.f), a1 = make_float2(0.f, 0.f);
    const uint* sp = hBf + lane;
    int nin = n < 64 ? n : 64;
    int i = 0;
    for (; i + 4 <= nin; i += 4) {
        int s0 = __shfl((int)meta.x, i,     64);
        int s1 = __shfl((int)meta.x, i + 1, 64);
        int s2 = __shfl((int)meta.x, i + 2, 64);
        int s3 = __shfl((int)meta.x, i + 3, 64);
        unsigned x0 = sp[(size_t)s0 << 6];
        unsigned x1 = sp[(size_t)s1 << 6];
        unsigned x2 = sp[(size_t)s2 << 6];
        unsigned x3 = sp[(size_t)s3 << 6];
        float v0 = __uint_as_float((unsigned)__shfl((int)meta.y, i,     64));
        float v1 = __uint_as_float((unsigned)__shfl((int)meta.y, i + 1, 64));
        float v2 = __uint_as_float((unsigned)__shfl((int)meta.y, i + 2, 64));
        float v3 = __uint_as_float((unsigned)__shfl((int)meta.y, i + 3, 64));
        float2 u;
        u = unpack_bf16(x0); a0.x += v0 * u.x; a0.y += v0 * u.y;
        u = unpack_bf16(x1); a1.x += v1 * u.x; a1.y += v1 * u.y;
        u = unpack_bf16(x2); a0.x += v2 * u.x; a0.y += v2 * u.y;
        u = unpack_bf16(x3); a1.x += v3 * u.x; a1.y += v3 * u.y;
    }
    for (; i < nin; i++) {
        int s = __shfl((int)meta.x, i, 64);
        float v = __uint_as_float((unsigned)__shfl((int)meta.y, i, 64));
        float2 u = unpack_bf16(sp[(size_t)s << 6]);
        a0.x += v * u.x; a0.y += v * u.y;
    }
    for (int k = 64; k < n; k++) {
        uint2 e = edges[beg + k];
        float v = __uint_as_float(e.y);
        float2 u = unpack_bf16(sp[(size_t)e.x << 6]);
        a0.x += v * u.x; a0.y += v * u.y;
    }
    float2 acc = make_float2(a0.x + a1.x, a0.y + a1.y);
    float s = acc.x + acc.y;
    float sq = acc.x * acc.x + acc.y * acc.y;
    #pragma unroll
    for (int o = 32; o > 0; o >>= 1) {
        s  += __shfl_xor(s, o, 64);
        sq += __shfl_xor(sq, o, 64);
    }
    float mu = s * (1.0f / DIM);
    float var = sq * (1.0f / DIM) - mu * mu;
    float rs = rsqrtf(var + 1e-5f);
    float2 g  = ((const float2*)gamma)[lane];
    float2 bb = ((const float2*)beta)[lane];
    float2 e2 = unpack_bf16(egoBf[(size_t)row * 64 + lane]);
    float2 o2;
    o2.x = (acc.x - mu) * rs * g.x + bb.x + e2.x;
    o2.y = (acc.y - mu) * rs * g.y + bb.y + e2.y;
    ((float2*)out)[(size_t)row * 64 + lane] = o2;
}

// ---------- fallback: atomic scatter path (ws too small) ----------
__device__ __forceinline__ void atomic_add_f32(float* p, float v) {
    __hip_atomic_fetch_add(p, v, __ATOMIC_RELAXED, __HIP_MEMORY_SCOPE_AGENT);
}
__global__ void scatter_kernel(const float* __restrict__ src, const float* __restrict__ vals,
                               const int* __restrict__ gidx, const int* __restrict__ sidx,
                               float* __restrict__ dst, int nnz) {
    int gid = blockIdx.x * blockDim.x + threadIdx.x;
    int e = gid >> 5, lane = gid & 31;
    if (e >= nnz) return;
    float v = vals[e];
    float4 x = ((const float4*)(src + (size_t)gidx[e] * DIM))[lane];
    float* d = dst + (size_t)sidx[e] * DIM + lane * 4;
    atomic_add_f32(d + 0, v * x.x); atomic_add_f32(d + 1, v * x.y);
    atomic_add_f32(d + 2, v * x.z); atomic_add_f32(d + 3, v * x.w);
}
__global__ void ln_residual_kernel(const float* __restrict__ h2, const float* __restrict__ ego,
                                   const float* __restrict__ gamma, const float* __restrict__ beta,
                                   float* __restrict__ out, int nrows) {
    int gid = blockIdx.x * blockDim.x + threadIdx.x;
    int row = gid >> 6, lane = gid & 63;
    if (row >= nrows) return;
    float2 x = ((const float2*)(h2 + (size_t)row * DIM))[lane];
    float s = x.x + x.y, sq = x.x * x.x + x.y * x.y;
    #pragma unroll
    for (int o = 32; o > 0; o >>= 1) { s += __shfl_xor(s, o, 64); sq += __shfl_xor(sq, o, 64); }
    float mu = s * (1.0f / DIM), var = sq * (1.0f / DIM) - mu * mu;
    float rs = rsqrtf(var + 1e-5f);
    float2 eg = ((const float2*)(ego + (size_t)row * DIM))[lane];
    float2 g = ((const float2*)gamma)[lane], b = ((const float2*)beta)[lane];
    float2 o2;
    o2.x = (x.x - mu) * rs * g.x + b.x + eg.x;
    o2.y = (x.y - mu) * rs * g.y + b.y + eg.y;
    ((float2*)(out + (size_t)row * DIM))[lane] = o2;
}

// ---------- launch ----------
extern "C" void kernel_launch(void* const* d_in, const int* in_sizes, int n_in,
                              void* d_out, int out_size, void* d_ws, size_t ws_size,
                              hipStream_t stream) {
    const float* ego   = (const float*)d_in[0];
    const float* vals  = (const float*)d_in[1];
    const float* gamma = (const float*)d_in[2];
    const float* beta  = (const float*)d_in[3];
    const int*   rows  = (const int*)d_in[4];
    const int*   cols  = (const int*)d_in[5];
    float* out = (float*)d_out;

    const size_t EGO_BF_B = (size_t)N_TOTAL * DIM * 2;               // 38.4 MB
    const size_t SLAB_B   = (size_t)2 * NNZ_E * sizeof(uint2);       // 24 MB
    const size_t H_BF_B   = (size_t)N_TOTAL * DIM * 2;               // 38.4 MB
    const size_t REGION_B = (SLAB_B > H_BF_B) ? SLAB_B : H_BF_B;     // hBf aliases dead slab
    const size_t SORT_B   = (size_t)2 * NNZ_E * sizeof(uint2);       // 24 MB
    const size_t OFFS_B   = ((size_t)N_TOTAL + 16) * sizeof(int);    // ~0.6 MB each
    const size_t SMALL    = 16384;
    const size_t REQ = EGO_BF_B + REGION_B + SORT_B + 2 * OFFS_B + SMALL;   // ~102 MB
    const size_t H_FP32_B = (size_t)N_TOTAL * DIM * sizeof(float);   // fallback: 76.8 MB

    char* w = (char*)d_ws;
    uint* egoBf   = (uint*)w;   w += EGO_BF_B;
    char* region  = w;          w += REGION_B;
    uint2* slab   = (uint2*)region;      // live: phaseA_fused -> phaseB
    uint* hBf     = (uint*)region;       // live: gather1 -> gather2 (slab dead by then)
    uint2* sorted = (uint2*)w;  w += SORT_B;
    int* offs1    = (int*)w;    w += OFFS_B;
    int* offs2    = (int*)w;    w += OFFS_B;
    int* cntArr   = (int*)w;    w += 512 * sizeof(int);
    int* sb       = (int*)w;    w += 516 * sizeof(int);
    int* gc       = (int*)w;    w += 512 * sizeof(int);

    if (ws_size >= REQ) {
        hipMemsetAsync(cntArr, 0, 512 * sizeof(int), stream);
        conv_bf16<<<(N_TOTAL * DIM / 8) / 256, 256, 0, stream>>>(ego, egoBf);
        coarse_hist<<<512, 256, 0, stream>>>(rows, cols, cntArr, cntArr + 256);
        scan_buckets<<<1, 256, 0, stream>>>(cntArr, sb, gc);
        phaseA_fused<<<A2_BLOCKS, 256, 0, stream>>>(rows, cols, vals, sb, gc, slab);
        phaseB<<<512, 256, 0, stream>>>(slab, sb, offs1, offs2, sorted);

        int ggrid = (N_TOTAL * 64) / 256;   // 37500
        gather1<<<ggrid, 256, 0, stream>>>(egoBf, offs1, sorted, hBf);
        gather2_ln<<<ggrid, 256, 0, stream>>>(hBf, offs2, sorted, egoBf, gamma, beta, out);
    } else {
        float* h = (float*)d_ws;            // fallback: fp32 h at ws start
        hipMemsetAsync(h, 0, H_FP32_B, stream);
        hipMemsetAsync(out, 0, H_FP32_B, stream);
        long total = (long)NNZ_E * 32;
        int grid = (int)((total + 255) / 256);
        scatter_kernel<<<grid, 256, 0, stream>>>(ego, vals, rows, cols, h, NNZ_E);
        scatter_kernel<<<grid, 256, 0, stream>>>(h, vals, cols, rows, out, NNZ_E);
        int lngrid = (N_TOTAL * 64 + 255) / 256;
        ln_residual_kernel<<<lngrid, 256, 0, stream>>>(out, ego, gamma, beta, out, N_TOTAL);
    }
}